// Round 11
// baseline (419.421 us; speedup 1.0000x reference)
//
#include <hip/hip_runtime.h>
#include <hip/hip_bf16.h>

typedef unsigned short u16;
typedef unsigned int u32;
typedef __attribute__((ext_vector_type(8))) short bf16x8;   // 8 bf16 (4 VGPRs)
typedef __attribute__((ext_vector_type(4))) short s16x4;
typedef __attribute__((ext_vector_type(4))) float f32x4;

#define NN 4096

__device__ __forceinline__ u16 f2bf(float f) {
    union { float f; u32 u; } v; v.f = f;
    u32 r = v.u + 0x7fffu + ((v.u >> 16) & 1u);   // RNE (inputs finite)
    return (u16)(r >> 16);
}

// ---------------- K1: deg = rowsum(A); inv_d = 1/(deg+1) ----------------
__global__ void rowsum_kernel(const float* __restrict__ A, float* __restrict__ invd) {
    const int row = blockIdx.x;
    const float4* a4 = reinterpret_cast<const float4*>(A + (size_t)row * NN);
    float s = 0.f;
    #pragma unroll
    for (int i = 0; i < 4; ++i) {
        float4 v = a4[threadIdx.x + i * 256];
        s += v.x + v.y + v.z + v.w;
    }
    #pragma unroll
    for (int off = 32; off > 0; off >>= 1) s += __shfl_down(s, off, 64);
    __shared__ float ws[4];
    if ((threadIdx.x & 63) == 0) ws[threadIdx.x >> 6] = s;
    __syncthreads();
    if (threadIdx.x == 0) {
        float t = ws[0] + ws[1] + ws[2] + ws[3];
        invd[row] = 1.0f / (t + 1.0f);
    }
}

// ------- K2: temp = 0.5*h + 0.5*(A + I)*inv_d[col]  -> bf16 [M][K] -------
__global__ void make_temp_kernel(const float* __restrict__ A, const float* __restrict__ h,
                                 const float* __restrict__ invd, u16* __restrict__ T) {
    const size_t g = ((size_t)blockIdx.x * 256 + threadIdx.x) * 8;
    const int row = (int)(g >> 12);
    const int col = (int)(g & 4095);
    const float4* a4 = reinterpret_cast<const float4*>(A + g);
    const float4* h4 = reinterpret_cast<const float4*>(h + g);
    const float4* d4 = reinterpret_cast<const float4*>(invd + col);
    float4 a0 = a4[0], a1 = a4[1];
    float4 h0 = h4[0], h1 = h4[1];
    float4 dd0 = d4[0], dd1 = d4[1];
    float av[8] = {a0.x,a0.y,a0.z,a0.w,a1.x,a1.y,a1.z,a1.w};
    float hv[8] = {h0.x,h0.y,h0.z,h0.w,h1.x,h1.y,h1.z,h1.w};
    float dv[8] = {dd0.x,dd0.y,dd0.z,dd0.w,dd1.x,dd1.y,dd1.z,dd1.w};
    bf16x8 o;
    #pragma unroll
    for (int j = 0; j < 8; ++j) {
        float aa = av[j] + ((col + j == row) ? 1.0f : 0.0f);
        float t = 0.5f * hv[j] + 0.5f * aa * dv[j];
        o[j] = (short)f2bf(t);
    }
    *reinterpret_cast<bf16x8*>(T + g) = o;
}

// --------- K3: Wt[n][k] = bf16(W[k][n])  (LDS 64x64 tile transpose) ---------
__global__ void transposeW_kernel(const float* __restrict__ W, u16* __restrict__ Wt) {
    __shared__ float tile[64][65];
    const int nt = blockIdx.x & 63;
    const int kt = blockIdx.x >> 6;
    const int k0 = kt * 64, n0 = nt * 64;
    const int tr = threadIdx.x >> 4;          // 0..15
    const int tc = (threadIdx.x & 15) * 4;    // 0..60
    #pragma unroll
    for (int rr = 0; rr < 64; rr += 16) {
        float4 v = *reinterpret_cast<const float4*>(&W[(size_t)(k0 + tr + rr) * NN + n0 + tc]);
        tile[tr + rr][tc + 0] = v.x;
        tile[tr + rr][tc + 1] = v.y;
        tile[tr + rr][tc + 2] = v.z;
        tile[tr + rr][tc + 3] = v.w;
    }
    __syncthreads();
    #pragma unroll
    for (int rr = 0; rr < 64; rr += 16) {
        const int n = tr + rr;
        s16x4 o;
        #pragma unroll
        for (int j = 0; j < 4; ++j) o[j] = (short)f2bf(tile[tc + j][n]);
        *reinterpret_cast<s16x4*>(&Wt[(size_t)(n0 + n) * NN + k0 + tc]) = o;
    }
}

// ============ K4: C[M][N] = temp[M][K] @ Wt[N][K]^T (bf16 MFMA) ============
// R11: 256x256 tile, 8 waves, BK=64. A via LDS (R5 path: XOR-8 swizzle,
// dbuf 64KB, stage t+1 at step start). B read DIRECTLY from L2 into a
// ping-pong register set: bn-grouped block mapping (bn = 2*(bid&7) +
// ((bid>>3)&1)) gives each XCD only 2 B-panels = 4MB = its L2 capacity
// (R9 failed because each XCD saw all 16 panels). DS-read traffic halves
// (192KB -> 128KB/tile); issue-to-wait distance = full step >> L2 latency.

#define GLD16(g, l) __builtin_amdgcn_global_load_lds( \
    (const __attribute__((address_space(1))) void*)(g), \
    (__attribute__((address_space(3))) void*)(l), 16, 0, 0)

__global__ __launch_bounds__(512) void gemm_kernel(
    const u16* __restrict__ Atl,   // [M][K] bf16 (temp)
    const u16* __restrict__ Btl,   // [N][K] bf16 (Wt)
    float* __restrict__ C)         // [M][N] f32
{
    __shared__ u16 SA[2][16384];   // [buf][256 rows x 64 k] = 64 KiB (A only)

    const int tid  = threadIdx.x;
    const int wid  = tid >> 6;     // 0..7
    const int lane = tid & 63;
    const int llo  = lane & 15;
    const int lhi  = lane >> 4;    // 0..3
    const int wr   = wid >> 2;     // 0..1  (M half: 128 rows)
    const int wc   = wid & 3;      // 0..3  (N quarter: 64 cols)

    // ---- bn-grouped XCD mapping (bijective over 256 blocks) ----
    // XCD x = bid&7 gets blocks with bn in {2x, 2x+1} only -> 4MB of B in L2.
    const int x  = (int)blockIdx.x & 7;
    const int ii = (int)blockIdx.x >> 3;       // 0..31
    const int bn = 2 * x + (ii & 1);
    const int bm = ii >> 1;                    // 0..15
    const int tileRow = bm * 256, tileCol = bn * 256;

    // ---- A staging (R5-proven): linear LDS dest, inverse-swizzled source ----
    const int r0 = tid >> 3;                                // 0..63
    const int kc = (((tid & 7) ^ (r0 & 7)) << 3);
    const u16* gA = Atl + (size_t)(tileRow + r0) * NN + kc;

    #define STAGE_A(BUF, KOFF) do { \
        _Pragma("unroll") \
        for (int i2 = 0; i2 < 4; ++i2) \
            GLD16(gA + (size_t)(i2 * 64) * NN + (KOFF), &SA[BUF][i2 * 4096 + tid * 8]); \
    } while (0)

    // ---- A read offsets (swizzled; ks1 = off ^ 32 elements) ----
    int offA[8];
    #pragma unroll
    for (int m = 0; m < 8; ++m) {
        const int row = wr * 128 + m * 16 + llo;
        offA[m] = row * 64 + ((lhi ^ (row & 7)) << 3);
    }

    // ---- B direct-from-L2 per-lane row pointers ----
    const u16* gBr[4];
    #pragma unroll
    for (int n = 0; n < 4; ++n)
        gBr[n] = Btl + (size_t)(tileCol + wc * 64 + n * 16 + llo) * NN + lhi * 8;

    #define BLOAD(SET, KB) do { \
        _Pragma("unroll") \
        for (int n = 0; n < 4; ++n) { \
            SET[n][0] = *reinterpret_cast<const bf16x8*>(gBr[n] + (KB)); \
            SET[n][1] = *reinterpret_cast<const bf16x8*>(gBr[n] + (KB) + 32); \
        } } while (0)

    f32x4 acc[8][4];
    #pragma unroll
    for (int m = 0; m < 8; ++m)
        #pragma unroll
        for (int n = 0; n < 4; ++n)
            acc[m][n] = (f32x4){0.f, 0.f, 0.f, 0.f};

    bf16x8 bE[4][2], bO[4][2];   // ping-pong B sets (static indexing only)

    // ---- prologue: stage A(0), load B(0) ----
    STAGE_A(0, 0);
    BLOAD(bE, 0);
    asm volatile("s_waitcnt vmcnt(0)" ::: "memory");
    __builtin_amdgcn_s_barrier();
    asm volatile("" ::: "memory");

    // STEP(T): issue A-stage(T+1) + B-load(T+1) at step START; compute from
    // LDS A-frags + B regs(T); vmcnt(0)+barrier at step END (full-step dist).
    #define STEP(T, BC, BNX) do { \
        const int t_ = (T); \
        const bool nlast_ = t_ < 63; \
        if (nlast_) { \
            STAGE_A((t_ + 1) & 1, (t_ + 1) * 64); \
            BLOAD(BNX, (t_ + 1) * 64); \
        } \
        __builtin_amdgcn_sched_barrier(0); \
        const u16* sA = &SA[t_ & 1][0]; \
        bf16x8 af[8]; \
        _Pragma("unroll") \
        for (int m = 0; m < 8; ++m) af[m] = *reinterpret_cast<const bf16x8*>(sA + offA[m]); \
        __builtin_amdgcn_s_setprio(1); \
        _Pragma("unroll") \
        for (int m = 0; m < 8; ++m) \
            _Pragma("unroll") \
            for (int n = 0; n < 4; ++n) \
                acc[m][n] = __builtin_amdgcn_mfma_f32_16x16x32_bf16(af[m], BC[n][0], acc[m][n], 0, 0, 0); \
        __builtin_amdgcn_s_setprio(0); \
        _Pragma("unroll") \
        for (int m = 0; m < 8; ++m) af[m] = *reinterpret_cast<const bf16x8*>(sA + (offA[m] ^ 32)); \
        __builtin_amdgcn_s_setprio(1); \
        _Pragma("unroll") \
        for (int m = 0; m < 8; ++m) \
            _Pragma("unroll") \
            for (int n = 0; n < 4; ++n) \
                acc[m][n] = __builtin_amdgcn_mfma_f32_16x16x32_bf16(af[m], BC[n][1], acc[m][n], 0, 0, 0); \
        __builtin_amdgcn_s_setprio(0); \
        if (nlast_) { \
            asm volatile("s_waitcnt vmcnt(0)" ::: "memory"); \
            __builtin_amdgcn_s_barrier(); \
            asm volatile("" ::: "memory"); \
        } \
    } while (0)

    #pragma unroll 1
    for (int tt = 0; tt < 32; ++tt) {
        STEP(2 * tt,     bE, bO);   // even: consume E, fill O
        STEP(2 * tt + 1, bO, bE);   // odd : consume O, fill E
    }
    #undef STEP
    #undef BLOAD
    #undef STAGE_A

    // ---- epilogue: C/D layout col=lane&15, row=(lane>>4)*4+reg ----
    #pragma unroll
    for (int m = 0; m < 8; ++m) {
        #pragma unroll
        for (int n = 0; n < 4; ++n) {
            const size_t rbase = (size_t)(tileRow + wr * 128 + m * 16 + lhi * 4) * NN
                               + tileCol + wc * 64 + n * 16 + llo;
            #pragma unroll
            for (int j = 0; j < 4; ++j)
                C[rbase + (size_t)j * NN] = acc[m][n][j];
        }
    }
}

// ---------------------------------------------------------------------------
extern "C" void kernel_launch(void* const* d_in, const int* in_sizes, int n_in,
                              void* d_out, int out_size, void* d_ws, size_t ws_size,
                              hipStream_t stream) {
    const float* A = (const float*)d_in[0];
    const float* h = (const float*)d_in[1];
    const float* W = (const float*)d_in[2];
    float* out = (float*)d_out;

    // workspace layout: inv_d (16KB) | temp bf16 (32MB) | Wt bf16 (32MB)
    float* invd = (float*)d_ws;
    u16* temp = (u16*)((char*)d_ws + 16384);
    u16* wt   = temp + (size_t)NN * NN;

    rowsum_kernel<<<NN, 256, 0, stream>>>(A, invd);
    make_temp_kernel<<<(NN * (size_t)NN) / (256 * 8), 256, 0, stream>>>(A, h, invd, temp);
    transposeW_kernel<<<(NN / 64) * (NN / 64), 256, 0, stream>>>(W, wt);
    gemm_kernel<<<256, 512, 0, stream>>>(temp, wt, out);
}

// Round 12
// 175.179 us; speedup vs baseline: 2.3942x; 2.3942x over previous
//
#include <hip/hip_runtime.h>
#include <hip/hip_bf16.h>

typedef unsigned short u16;
typedef unsigned int u32;
typedef __attribute__((ext_vector_type(8))) short bf16x8;   // 8 bf16 (4 VGPRs)
typedef __attribute__((ext_vector_type(4))) short s16x4;
typedef __attribute__((ext_vector_type(4))) float f32x4;

#define NN 4096

__device__ __forceinline__ u16 f2bf(float f) {
    union { float f; u32 u; } v; v.f = f;
    u32 r = v.u + 0x7fffu + ((v.u >> 16) & 1u);   // RNE (inputs finite)
    return (u16)(r >> 16);
}

// ---------------- K1: deg = rowsum(A); inv_d = 1/(deg+1) ----------------
__global__ void rowsum_kernel(const float* __restrict__ A, float* __restrict__ invd) {
    const int row = blockIdx.x;
    const float4* a4 = reinterpret_cast<const float4*>(A + (size_t)row * NN);
    float s = 0.f;
    #pragma unroll
    for (int i = 0; i < 4; ++i) {
        float4 v = a4[threadIdx.x + i * 256];
        s += v.x + v.y + v.z + v.w;
    }
    #pragma unroll
    for (int off = 32; off > 0; off >>= 1) s += __shfl_down(s, off, 64);
    __shared__ float ws[4];
    if ((threadIdx.x & 63) == 0) ws[threadIdx.x >> 6] = s;
    __syncthreads();
    if (threadIdx.x == 0) {
        float t = ws[0] + ws[1] + ws[2] + ws[3];
        invd[row] = 1.0f / (t + 1.0f);
    }
}

// ------- K2: temp = 0.5*h + 0.5*(A + I)*inv_d[col]  -> bf16 [M][K] -------
__global__ void make_temp_kernel(const float* __restrict__ A, const float* __restrict__ h,
                                 const float* __restrict__ invd, u16* __restrict__ T) {
    const size_t g = ((size_t)blockIdx.x * 256 + threadIdx.x) * 8;
    const int row = (int)(g >> 12);
    const int col = (int)(g & 4095);
    const float4* a4 = reinterpret_cast<const float4*>(A + g);
    const float4* h4 = reinterpret_cast<const float4*>(h + g);
    const float4* d4 = reinterpret_cast<const float4*>(invd + col);
    float4 a0 = a4[0], a1 = a4[1];
    float4 h0 = h4[0], h1 = h4[1];
    float4 dd0 = d4[0], dd1 = d4[1];
    float av[8] = {a0.x,a0.y,a0.z,a0.w,a1.x,a1.y,a1.z,a1.w};
    float hv[8] = {h0.x,h0.y,h0.z,h0.w,h1.x,h1.y,h1.z,h1.w};
    float dv[8] = {dd0.x,dd0.y,dd0.z,dd0.w,dd1.x,dd1.y,dd1.z,dd1.w};
    bf16x8 o;
    #pragma unroll
    for (int j = 0; j < 8; ++j) {
        float aa = av[j] + ((col + j == row) ? 1.0f : 0.0f);
        float t = 0.5f * hv[j] + 0.5f * aa * dv[j];
        o[j] = (short)f2bf(t);
    }
    *reinterpret_cast<bf16x8*>(T + g) = o;
}

// --------- K3: Wt[n][k] = bf16(W[k][n])  (LDS 64x64 tile transpose) ---------
__global__ void transposeW_kernel(const float* __restrict__ W, u16* __restrict__ Wt) {
    __shared__ float tile[64][65];
    const int nt = blockIdx.x & 63;
    const int kt = blockIdx.x >> 6;
    const int k0 = kt * 64, n0 = nt * 64;
    const int tr = threadIdx.x >> 4;          // 0..15
    const int tc = (threadIdx.x & 15) * 4;    // 0..60
    #pragma unroll
    for (int rr = 0; rr < 64; rr += 16) {
        float4 v = *reinterpret_cast<const float4*>(&W[(size_t)(k0 + tr + rr) * NN + n0 + tc]);
        tile[tr + rr][tc + 0] = v.x;
        tile[tr + rr][tc + 1] = v.y;
        tile[tr + rr][tc + 2] = v.z;
        tile[tr + rr][tc + 3] = v.w;
    }
    __syncthreads();
    #pragma unroll
    for (int rr = 0; rr < 64; rr += 16) {
        const int n = tr + rr;
        s16x4 o;
        #pragma unroll
        for (int j = 0; j < 4; ++j) o[j] = (short)f2bf(tile[tc + j][n]);
        *reinterpret_cast<s16x4*>(&Wt[(size_t)(n0 + n) * NN + k0 + tc]) = o;
    }
}

// ============ K4: C = temp @ Wt^T — 8-phase with STAGGERED half staging ======
// 256x256, BK=64, 2 bufs. One half-region staged per phase:
//   P1(g): A1(g+1) | P2(g): B1(g+1) | P3(g): B0(g+2) | P4(g): A0(g+2)
// vmcnt(4) once per tile at P4 (2 halves permanently in flight, never 0
// until tail). All WAR edges have >=1 barrier; vmcnt(4)@P4(g) lands all of
// tile g+1 before its first read. Reads 12/4/8/0, lgkm throttle, setprio.

#define GLD16(g, l) __builtin_amdgcn_global_load_lds( \
    (const __attribute__((address_space(1))) void*)(g), \
    (__attribute__((address_space(3))) void*)(l), 16, 0, 0)

#define SBAR()  do { __builtin_amdgcn_sched_barrier(0); \
    __builtin_amdgcn_s_barrier(); asm volatile("" ::: "memory"); } while (0)
#define LGKM0() do { asm volatile("s_waitcnt lgkmcnt(0)" ::: "memory"); \
    __builtin_amdgcn_sched_barrier(0); } while (0)

__global__ __launch_bounds__(512, 2) void gemm_kernel(
    const u16* __restrict__ Atl,   // [M][K] bf16 (temp)
    const u16* __restrict__ Btl,   // [N][K] bf16 (Wt)
    float* __restrict__ C)         // [M][N] f32
{
    __shared__ u16 S[2][4][8192];  // [buf][A0|A1|B0|B1][128 rows x 64 k]

    const int tid  = threadIdx.x;
    const int wid  = tid >> 6;     // 0..7
    const int lane = tid & 63;
    const int llo  = lane & 15;
    const int lhi  = lane >> 4;    // 0..3
    const int wr   = wid >> 2;     // 0..1  (A region wr)
    const int wc   = wid & 3;      // 0..3  (B region wc>>1, row-half wc&1)

    // XCD swizzle (grid=256, 256%8==0 -> bijective)
    const int swz = ((int)blockIdx.x & 7) * 32 + ((int)blockIdx.x >> 3);
    const int bm = swz >> 4, bn = swz & 15;
    const int tileRow = bm * 256, tileCol = bn * 256;

    // ---- staging: linear LDS dest, inverse-swizzled source (R5-proven) ----
    const int r0 = tid >> 3;                                // 0..63
    const int kc = (((tid & 7) ^ (r0 & 7)) << 3);
    const size_t R64  = (size_t)64 * NN;
    const size_t R128 = (size_t)128 * NN;
    const u16* gA = Atl + (size_t)(tileRow + r0) * NN + kc;
    const u16* gB = Btl + (size_t)(tileCol + r0) * NN + kc;

    // stage one 128x64 half-region = 2 gld
    #define STG(PTR, DSTBASE) do { \
        GLD16((PTR),       (DSTBASE) + tid * 8); \
        GLD16((PTR) + R64, (DSTBASE) + 4096 + tid * 8); } while (0)

    // ---- swizzled read offsets (region-relative; ks1 = off^32) ----
    int offA[8], offB[4];
    #pragma unroll
    for (int m = 0; m < 8; ++m) {
        const int row = m * 16 + llo;
        offA[m] = row * 64 + ((lhi ^ (row & 7)) << 3);
    }
    #pragma unroll
    for (int n = 0; n < 4; ++n) {
        const int row = (wc & 1) * 64 + n * 16 + llo;
        offB[n] = row * 64 + ((lhi ^ (row & 7)) << 3);
    }

    f32x4 acc[8][4];
    #pragma unroll
    for (int m = 0; m < 8; ++m)
        #pragma unroll
        for (int n = 0; n < 4; ++n)
            acc[m][n] = (f32x4){0.f, 0.f, 0.f, 0.f};

    u16* const B0p = (u16*)&S[0][0][0];
    u16* const B1p = (u16*)&S[1][0][0];

    // ---- prologue: tile0 full (buf0) + A0(1), B0(1) (buf1) ----
    STG(gA,             B0p + 0 * 8192);   // A0(0)
    STG(gA + R128,      B0p + 1 * 8192);   // A1(0)
    STG(gB,             B0p + 2 * 8192);   // B0(0)
    STG(gB + R128,      B0p + 3 * 8192);   // B1(0)
    STG(gA + 64,        B1p + 0 * 8192);   // A0(1)
    STG(gB + 64,        B1p + 2 * 8192);   // B0(1)
    asm volatile("s_waitcnt vmcnt(4)" ::: "memory");   // tile0 landed
    __builtin_amdgcn_s_barrier();
    asm volatile("" ::: "memory");

    #pragma unroll 1
    for (int g = 0; g < 64; ++g) {
        u16* cb = (g & 1) ? B1p : B0p;     // buf of tile g (P3/P4 stage here for g+2)
        u16* nb = (g & 1) ? B0p : B1p;     // buf of tile g+1 (P1/P2 stage here)
        const u16* sAr = cb + wr * 8192;
        const u16* sBr = cb + (2 + (wc >> 1)) * 8192;
        const int k1 = (g + 1) * 64;       // k-offset of tile g+1
        const int k2 = (g + 2) * 64;

        bf16x8 a0[4][2], a1[4][2], b0[2][2], b1[2][2];

        // ===== P1: read A[0-3]+B[0-1] (12) | stage A1(g+1) | MFMA m0-3 x n0-1
        #pragma unroll
        for (int m = 0; m < 4; ++m) {
            a0[m][0] = *reinterpret_cast<const bf16x8*>(sAr + offA[m]);
            a0[m][1] = *reinterpret_cast<const bf16x8*>(sAr + (offA[m] ^ 32));
        }
        #pragma unroll
        for (int n = 0; n < 2; ++n) {
            b0[n][0] = *reinterpret_cast<const bf16x8*>(sBr + offB[n]);
            b0[n][1] = *reinterpret_cast<const bf16x8*>(sBr + (offB[n] ^ 32));
        }
        if (g <= 62) STG(gA + R128 + k1, nb + 1 * 8192);
        asm volatile("s_waitcnt lgkmcnt(8)" ::: "memory");
        SBAR();
        LGKM0();
        __builtin_amdgcn_s_setprio(1);
        #pragma unroll
        for (int ks = 0; ks < 2; ++ks)
            #pragma unroll
            for (int m = 0; m < 4; ++m)
                #pragma unroll
                for (int n = 0; n < 2; ++n)
                    acc[m][n] = __builtin_amdgcn_mfma_f32_16x16x32_bf16(a0[m][ks], b0[n][ks], acc[m][n], 0, 0, 0);
        __builtin_amdgcn_s_setprio(0);
        SBAR();

        // ===== P2: read B[2-3] (4) | stage B1(g+1) | MFMA m0-3 x n2-3 =====
        #pragma unroll
        for (int n = 0; n < 2; ++n) {
            b1[n][0] = *reinterpret_cast<const bf16x8*>(sBr + offB[2 + n]);
            b1[n][1] = *reinterpret_cast<const bf16x8*>(sBr + (offB[2 + n] ^ 32));
        }
        if (g <= 62) STG(gB + R128 + k1, nb + 3 * 8192);
        SBAR();
        LGKM0();
        __builtin_amdgcn_s_setprio(1);
        #pragma unroll
        for (int ks = 0; ks < 2; ++ks)
            #pragma unroll
            for (int m = 0; m < 4; ++m)
                #pragma unroll
                for (int n = 0; n < 2; ++n)
                    acc[m][2 + n] = __builtin_amdgcn_mfma_f32_16x16x32_bf16(a0[m][ks], b1[n][ks], acc[m][2 + n], 0, 0, 0);
        __builtin_amdgcn_s_setprio(0);
        SBAR();

        // ===== P3: read A[4-7] (8) | stage B0(g+2) | MFMA m4-7 x n0-1 =====
        // B0(g) reads finished at P2's closing barrier -> WAR-safe (same buf).
        #pragma unroll
        for (int m = 0; m < 4; ++m) {
            a1[m][0] = *reinterpret_cast<const bf16x8*>(sAr + offA[4 + m]);
            a1[m][1] = *reinterpret_cast<const bf16x8*>(sAr + (offA[4 + m] ^ 32));
        }
        if (g <= 61) STG(gB + k2, cb + 2 * 8192);
        SBAR();
        LGKM0();
        __builtin_amdgcn_s_setprio(1);
        #pragma unroll
        for (int ks = 0; ks < 2; ++ks)
            #pragma unroll
            for (int m = 0; m < 4; ++m)
                #pragma unroll
                for (int n = 0; n < 2; ++n)
                    acc[4 + m][n] = __builtin_amdgcn_mfma_f32_16x16x32_bf16(a1[m][ks], b0[n][ks], acc[4 + m][n], 0, 0, 0);
        __builtin_amdgcn_s_setprio(0);
        SBAR();

        // ===== P4: stage A0(g+2) | vmcnt(4) | MFMA m4-7 x n2-3 =====
        // A0(g) reads finished at P3's closing barrier -> WAR-safe.
        if (g <= 61) STG(gA + k2, cb + 0 * 8192);
        if (g <= 61)      asm volatile("s_waitcnt vmcnt(4)" ::: "memory");  // tile g+1 landed
        else if (g == 62) asm volatile("s_waitcnt vmcnt(0)" ::: "memory");  // drain tile 63
        SBAR();
        __builtin_amdgcn_s_setprio(1);
        #pragma unroll
        for (int ks = 0; ks < 2; ++ks)
            #pragma unroll
            for (int m = 0; m < 4; ++m)
                #pragma unroll
                for (int n = 0; n < 2; ++n)
                    acc[4 + m][2 + n] = __builtin_amdgcn_mfma_f32_16x16x32_bf16(a1[m][ks], b1[n][ks], acc[4 + m][2 + n], 0, 0, 0);
        __builtin_amdgcn_s_setprio(0);
        if (g < 63) SBAR();
    }
    #undef STG

    // ---- epilogue: C/D layout col=lane&15, row=(lane>>4)*4+reg ----
    #pragma unroll
    for (int m = 0; m < 8; ++m) {
        #pragma unroll
        for (int n = 0; n < 4; ++n) {
            const size_t rbase = (size_t)(tileRow + wr * 128 + m * 16 + lhi * 4) * NN
                               + tileCol + wc * 64 + n * 16 + llo;
            #pragma unroll
            for (int j = 0; j < 4; ++j)
                C[rbase + (size_t)j * NN] = acc[m][n][j];
        }
    }
}

// ---------------------------------------------------------------------------
extern "C" void kernel_launch(void* const* d_in, const int* in_sizes, int n_in,
                              void* d_out, int out_size, void* d_ws, size_t ws_size,
                              hipStream_t stream) {
    const float* A = (const float*)d_in[0];
    const float* h = (const float*)d_in[1];
    const float* W = (const float*)d_in[2];
    float* out = (float*)d_out;

    // workspace layout: inv_d (16KB) | temp bf16 (32MB) | Wt bf16 (32MB)
    float* invd = (float*)d_ws;
    u16* temp = (u16*)((char*)d_ws + 16384);
    u16* wt   = temp + (size_t)NN * NN;

    rowsum_kernel<<<NN, 256, 0, stream>>>(A, invd);
    make_temp_kernel<<<(NN * (size_t)NN) / (256 * 8), 256, 0, stream>>>(A, h, invd, temp);
    transposeW_kernel<<<(NN / 64) * (NN / 64), 256, 0, stream>>>(W, wt);
    gemm_kernel<<<256, 512, 0, stream>>>(temp, wt, out);
}

// Round 13
// 168.988 us; speedup vs baseline: 2.4820x; 1.0366x over previous
//
#include <hip/hip_runtime.h>
#include <hip/hip_bf16.h>

typedef unsigned short u16;
typedef unsigned int u32;
typedef __attribute__((ext_vector_type(8))) short bf16x8;   // 8 bf16 (4 VGPRs)
typedef __attribute__((ext_vector_type(4))) short s16x4;
typedef __attribute__((ext_vector_type(4))) float f32x4;

#define NN 4096

__device__ __forceinline__ u16 f2bf(float f) {
    union { float f; u32 u; } v; v.f = f;
    u32 r = v.u + 0x7fffu + ((v.u >> 16) & 1u);   // RNE (inputs finite)
    return (u16)(r >> 16);
}

// ---------------- K1: deg = rowsum(A); inv_d = 1/(deg+1) ----------------
__global__ void rowsum_kernel(const float* __restrict__ A, float* __restrict__ invd) {
    const int row = blockIdx.x;
    const float4* a4 = reinterpret_cast<const float4*>(A + (size_t)row * NN);
    float s = 0.f;
    #pragma unroll
    for (int i = 0; i < 4; ++i) {
        float4 v = a4[threadIdx.x + i * 256];
        s += v.x + v.y + v.z + v.w;
    }
    #pragma unroll
    for (int off = 32; off > 0; off >>= 1) s += __shfl_down(s, off, 64);
    __shared__ float ws[4];
    if ((threadIdx.x & 63) == 0) ws[threadIdx.x >> 6] = s;
    __syncthreads();
    if (threadIdx.x == 0) {
        float t = ws[0] + ws[1] + ws[2] + ws[3];
        invd[row] = 1.0f / (t + 1.0f);
    }
}

// ------- K2: temp = 0.5*h + 0.5*(A + I)*inv_d[col]  -> bf16 [M][K] -------
__global__ void make_temp_kernel(const float* __restrict__ A, const float* __restrict__ h,
                                 const float* __restrict__ invd, u16* __restrict__ T) {
    const size_t g = ((size_t)blockIdx.x * 256 + threadIdx.x) * 8;
    const int row = (int)(g >> 12);
    const int col = (int)(g & 4095);
    const float4* a4 = reinterpret_cast<const float4*>(A + g);
    const float4* h4 = reinterpret_cast<const float4*>(h + g);
    const float4* d4 = reinterpret_cast<const float4*>(invd + col);
    float4 a0 = a4[0], a1 = a4[1];
    float4 h0 = h4[0], h1 = h4[1];
    float4 dd0 = d4[0], dd1 = d4[1];
    float av[8] = {a0.x,a0.y,a0.z,a0.w,a1.x,a1.y,a1.z,a1.w};
    float hv[8] = {h0.x,h0.y,h0.z,h0.w,h1.x,h1.y,h1.z,h1.w};
    float dv[8] = {dd0.x,dd0.y,dd0.z,dd0.w,dd1.x,dd1.y,dd1.z,dd1.w};
    bf16x8 o;
    #pragma unroll
    for (int j = 0; j < 8; ++j) {
        float aa = av[j] + ((col + j == row) ? 1.0f : 0.0f);
        float t = 0.5f * hv[j] + 0.5f * aa * dv[j];
        o[j] = (short)f2bf(t);
    }
    *reinterpret_cast<bf16x8*>(T + g) = o;
}

// --------- K3: Wt[n][k] = bf16(W[k][n])  (LDS 64x64 tile transpose) ---------
__global__ void transposeW_kernel(const float* __restrict__ W, u16* __restrict__ Wt) {
    __shared__ float tile[64][65];
    const int nt = blockIdx.x & 63;
    const int kt = blockIdx.x >> 6;
    const int k0 = kt * 64, n0 = nt * 64;
    const int tr = threadIdx.x >> 4;          // 0..15
    const int tc = (threadIdx.x & 15) * 4;    // 0..60
    #pragma unroll
    for (int rr = 0; rr < 64; rr += 16) {
        float4 v = *reinterpret_cast<const float4*>(&W[(size_t)(k0 + tr + rr) * NN + n0 + tc]);
        tile[tr + rr][tc + 0] = v.x;
        tile[tr + rr][tc + 1] = v.y;
        tile[tr + rr][tc + 2] = v.z;
        tile[tr + rr][tc + 3] = v.w;
    }
    __syncthreads();
    #pragma unroll
    for (int rr = 0; rr < 64; rr += 16) {
        const int n = tr + rr;
        s16x4 o;
        #pragma unroll
        for (int j = 0; j < 4; ++j) o[j] = (short)f2bf(tile[tc + j][n]);
        *reinterpret_cast<s16x4*>(&Wt[(size_t)(n0 + n) * NN + k0 + tc]) = o;
    }
}

// ============ K4: C[M][N] = temp[M][K] @ Wt[N][K]^T (bf16 MFMA) ============
// R13 = R5 skeleton (256x256, BK=64, 2 LDS bufs, stage-at-start, single
// vmcnt(0)+barrier per K-tile, XOR-8 swizzle) with the compute section
// SOFTWARE-PIPELINED: upfront B[8]+A-row0 reads only (the true RAW deps);
// A(mf+1) reads issue during row-mf MFMAs (sched_barrier-pinned), so ~60%
// of DS reads hide under the MFMA stream instead of bursting post-barrier.

#define GLD16(g, l) __builtin_amdgcn_global_load_lds( \
    (const __attribute__((address_space(1))) void*)(g), \
    (__attribute__((address_space(3))) void*)(l), 16, 0, 0)

__global__ __launch_bounds__(512, 2) void gemm_kernel(
    const u16* __restrict__ Atl,   // [M][K] bf16 (temp)
    const u16* __restrict__ Btl,   // [N][K] bf16 (Wt)
    float* __restrict__ C)         // [M][N] f32
{
    __shared__ u16 S[2][2][16384]; // [buf][A=0/B=1][256 rows x 64 k] = 128 KiB

    const int tid  = threadIdx.x;
    const int wid  = tid >> 6;     // 0..7
    const int lane = tid & 63;
    const int llo  = lane & 15;
    const int lhi  = lane >> 4;    // 0..3
    const int wr   = wid >> 2;     // 0..1  (M half: 128 rows)
    const int wc   = wid & 3;      // 0..3  (N quarter: 64 cols)

    // XCD swizzle (grid=256, 256%8==0 -> bijective)
    const int swz = ((int)blockIdx.x & 7) * 32 + ((int)blockIdx.x >> 3);
    const int bm = swz >> 4, bn = swz & 15;
    const int tileRow = bm * 256, tileCol = bn * 256;

    // ---- staging: linear LDS dest, inverse-swizzled global source ----
    const int r0 = tid >> 3;                                // 0..63
    const int kc = (((tid & 7) ^ (r0 & 7)) << 3);
    const u16* gA = Atl + (size_t)(tileRow + r0) * NN + kc;
    const u16* gB = Btl + (size_t)(tileCol + r0) * NN + kc;

    #define STAGE_TILE(buf, koff) do { \
        _Pragma("unroll") \
        for (int i = 0; i < 4; ++i) { \
            GLD16(gA + (size_t)(i * 64) * NN + (koff), &S[buf][0][i * 4096 + tid * 8]); \
            GLD16(gB + (size_t)(i * 64) * NN + (koff), &S[buf][1][i * 4096 + tid * 8]); \
        } } while (0)

    // ---- swizzled read offsets (elements; ks1 = off ^ 32) ----
    int offA[8], offB[4];
    #pragma unroll
    for (int m = 0; m < 8; ++m) {
        const int row = wr * 128 + m * 16 + llo;
        offA[m] = row * 64 + ((lhi ^ (row & 7)) << 3);
    }
    #pragma unroll
    for (int n = 0; n < 4; ++n) {
        const int row = wc * 64 + n * 16 + llo;
        offB[n] = row * 64 + ((lhi ^ (row & 7)) << 3);
    }

    f32x4 acc[8][4];
    #pragma unroll
    for (int m = 0; m < 8; ++m)
        #pragma unroll
        for (int n = 0; n < 4; ++n)
            acc[m][n] = (f32x4){0.f, 0.f, 0.f, 0.f};

    // ---- prologue: stage tile 0 into buf 0 ----
    STAGE_TILE(0, 0);
    asm volatile("s_waitcnt vmcnt(0)" ::: "memory");
    __builtin_amdgcn_s_barrier();
    asm volatile("" ::: "memory");

    // ---- main loop: 64 K-steps of 64 ----
    #pragma unroll 1
    for (int t = 0; t < 64; ++t) {
        if (t < 63) STAGE_TILE((t + 1) & 1, (t + 1) * 64);
        __builtin_amdgcn_sched_barrier(0);   // pin stage-issue first

        const u16* sA = &S[t & 1][0][0];
        const u16* sB = &S[t & 1][1][0];

        // upfront: only the true RAW deps — all B frags + A row 0
        bf16x8 bv[4][2];
        #pragma unroll
        for (int n = 0; n < 4; ++n) {
            bv[n][0] = *reinterpret_cast<const bf16x8*>(sB + offB[n]);
            bv[n][1] = *reinterpret_cast<const bf16x8*>(sB + (offB[n] ^ 32));
        }
        bf16x8 aC0 = *reinterpret_cast<const bf16x8*>(sA + offA[0]);
        bf16x8 aC1 = *reinterpret_cast<const bf16x8*>(sA + (offA[0] ^ 32));
        __builtin_amdgcn_sched_barrier(0);

        // pipelined mf loop: issue A(mf+1) reads, then MFMA row mf.
        #pragma unroll
        for (int m = 0; m < 8; ++m) {
            bf16x8 aN0, aN1;
            if (m < 7) {
                aN0 = *reinterpret_cast<const bf16x8*>(sA + offA[m + 1]);
                aN1 = *reinterpret_cast<const bf16x8*>(sA + (offA[m + 1] ^ 32));
            }
            __builtin_amdgcn_sched_barrier(0);
            __builtin_amdgcn_s_setprio(1);
            #pragma unroll
            for (int n = 0; n < 4; ++n)
                acc[m][n] = __builtin_amdgcn_mfma_f32_16x16x32_bf16(
                    aC0, bv[n][0], acc[m][n], 0, 0, 0);
            #pragma unroll
            for (int n = 0; n < 4; ++n)
                acc[m][n] = __builtin_amdgcn_mfma_f32_16x16x32_bf16(
                    aC1, bv[n][1], acc[m][n], 0, 0, 0);
            __builtin_amdgcn_s_setprio(0);
            __builtin_amdgcn_sched_barrier(0);
            if (m < 7) { aC0 = aN0; aC1 = aN1; }
        }

        // loads for tile t+1 were issued a full step (~3600 cy) ago -> ~free
        if (t < 63) {
            asm volatile("s_waitcnt vmcnt(0)" ::: "memory");
            __builtin_amdgcn_s_barrier();
            asm volatile("" ::: "memory");
        }
    }
    #undef STAGE_TILE

    // ---- epilogue: C/D layout col=lane&15, row=(lane>>4)*4+reg ----
    #pragma unroll
    for (int m = 0; m < 8; ++m) {
        #pragma unroll
        for (int n = 0; n < 4; ++n) {
            const size_t rbase = (size_t)(tileRow + wr * 128 + m * 16 + lhi * 4) * NN
                               + tileCol + wc * 64 + n * 16 + llo;
            #pragma unroll
            for (int j = 0; j < 4; ++j)
                C[rbase + (size_t)j * NN] = acc[m][n][j];
        }
    }
}

// ---------------------------------------------------------------------------
extern "C" void kernel_launch(void* const* d_in, const int* in_sizes, int n_in,
                              void* d_out, int out_size, void* d_ws, size_t ws_size,
                              hipStream_t stream) {
    const float* A = (const float*)d_in[0];
    const float* h = (const float*)d_in[1];
    const float* W = (const float*)d_in[2];
    float* out = (float*)d_out;

    // workspace layout: inv_d (16KB) | temp bf16 (32MB) | Wt bf16 (32MB)
    float* invd = (float*)d_ws;
    u16* temp = (u16*)((char*)d_ws + 16384);
    u16* wt   = temp + (size_t)NN * NN;

    rowsum_kernel<<<NN, 256, 0, stream>>>(A, invd);
    make_temp_kernel<<<(NN * (size_t)NN) / (256 * 8), 256, 0, stream>>>(A, h, invd, temp);
    transposeW_kernel<<<(NN / 64) * (NN / 64), 256, 0, stream>>>(W, wt);
    gemm_kernel<<<256, 512, 0, stream>>>(temp, wt, out);
}